// Round 7
// baseline (82.194 us; speedup 1.0000x reference)
//
#include <hip/hip_runtime.h>

#define NN 8192      // nodes (2 * batch)
#define NEDGE 524288 // total ragged neighbors
#define EMB 128
#define TILE 512     // edge-index LDS tile
#define LDP 260      // padded LDS row stride (bf16 elems): 2-row stride = 4 words mod 32

typedef __attribute__((ext_vector_type(8))) short bf16x8;
typedef __attribute__((ext_vector_type(4))) float f32x4;

__device__ __forceinline__ ushort f2bf(float f) {
    union { float f; uint u; } v; v.f = f;
    return (ushort)((v.u + 0x7FFF + ((v.u >> 16) & 1)) >> 16);  // RNE
}

// ---------------------------------------------------------------------------
// K1: fused prep + ragged aggregation (R4 structure, 8-deep unroll).
//  blocks [0,NN): one block per node, 256 threads = 8 groups x 32 lanes.
//  blocks [NN,NN+256): weight prep (bf16 convert, native [n][k] layout).
// ---------------------------------------------------------------------------
__global__ __launch_bounds__(256) void k_agg_prep(
    const int* __restrict__ entities,
    const int* __restrict__ nbr_ent,
    const int* __restrict__ nbr_rel,
    const int* __restrict__ offsets,
    const float* __restrict__ ent_emb,
    const float* __restrict__ rel_emb,
    const float* __restrict__ Wt,   // [256][128]
    const float* __restrict__ Wn,   // [256][256]
    const float* __restrict__ bt,
    const float* __restrict__ bn,
    const float* __restrict__ Wr,   // [256][512]
    ushort* __restrict__ Xcat,      // [NN][384] bf16
    ushort* __restrict__ Wb1,       // [256][384] bf16
    float* __restrict__ bias1,      // [256]
    ushort* __restrict__ Wb2)       // [256][512] bf16
{
    const int blk = blockIdx.x;
    if (blk >= NN) {                      // ---- weight-prep blocks ----
        const int j = blk - NN;           // 0..255
        const int t = threadIdx.x;
        for (int c = t; c < 384; c += 256) {
            const float v = (c < 128) ? Wt[(size_t)j * 128 + c]
                                      : Wn[(size_t)j * 256 + (c - 128)];
            Wb1[(size_t)j * 384 + c] = f2bf(v);
        }
        for (int c = t; c < 512; c += 256)
            Wb2[(size_t)j * 512 + c] = f2bf(Wr[(size_t)j * 512 + c]);
        if (t == 0) bias1[j] = bt[j] + bn[j];
        return;
    }

    // ---- aggregation blocks ----
    const int node  = blk;
    const int start = offsets[node];
    const int end   = (node + 1 < NN) ? offsets[node + 1] : NEDGE;
    const int cnt   = end - start;

    const int g    = threadIdx.x >> 5;   // 0..7
    const int lane = threadIdx.x & 31;   // 0..31
    const int c    = lane * 4;

    __shared__ int   sie[TILE];
    __shared__ int   sir[TILE];
    __shared__ float se[8][32][4];
    __shared__ float sr[8][32][4];

    float4 ae = make_float4(0.f, 0.f, 0.f, 0.f);
    float4 ar = make_float4(0.f, 0.f, 0.f, 0.f);

    for (int tb = start; tb < end; tb += TILE) {
        const int n = min(end - tb, TILE);
        __syncthreads();                                   // sie reusable
        for (int i = threadIdx.x; i < n; i += 256) {
            sie[i] = nbr_ent[tb + i];
            sir[i] = nbr_rel[tb + i];
        }
        __syncthreads();

        for (int i = g; i < n; i += 64) {
            int   idx[8];
            float msk[8];
            #pragma unroll
            for (int j = 0; j < 8; ++j) {
                const int v = (j == 0) ? 1 : (i + 8 * j < n);
                idx[j] = v ? (i + 8 * j) : i;
                msk[j] = (float)v;
            }
            float4 ve[8], vr[8];
            #pragma unroll
            for (int j = 0; j < 8; ++j)
                ve[j] = *(const float4*)(ent_emb + (size_t)sie[idx[j]] * EMB + c);
            #pragma unroll
            for (int j = 0; j < 8; ++j)
                vr[j] = *(const float4*)(rel_emb + (size_t)sir[idx[j]] * EMB + c);
            #pragma unroll
            for (int j = 0; j < 8; ++j) {
                ae.x = fmaf(msk[j], ve[j].x, ae.x);
                ae.y = fmaf(msk[j], ve[j].y, ae.y);
                ae.z = fmaf(msk[j], ve[j].z, ae.z);
                ae.w = fmaf(msk[j], ve[j].w, ae.w);
                ar.x = fmaf(msk[j], vr[j].x, ar.x);
                ar.y = fmaf(msk[j], vr[j].y, ar.y);
                ar.z = fmaf(msk[j], vr[j].z, ar.z);
                ar.w = fmaf(msk[j], vr[j].w, ar.w);
            }
        }
    }

    se[g][lane][0] = ae.x; se[g][lane][1] = ae.y;
    se[g][lane][2] = ae.z; se[g][lane][3] = ae.w;
    sr[g][lane][0] = ar.x; sr[g][lane][1] = ar.y;
    sr[g][lane][2] = ar.z; sr[g][lane][3] = ar.w;
    __syncthreads();

    ushort* xrow = Xcat + (size_t)node * 384;
    if (threadIdx.x < 32) {
        const int l = threadIdx.x;
        float4 te = make_float4(0.f, 0.f, 0.f, 0.f);
        float4 tr = make_float4(0.f, 0.f, 0.f, 0.f);
        #pragma unroll
        for (int o = 0; o < 8; ++o) {
            te.x += se[o][l][0]; te.y += se[o][l][1];
            te.z += se[o][l][2]; te.w += se[o][l][3];
            tr.x += sr[o][l][0]; tr.y += sr[o][l][1];
            tr.z += sr[o][l][2]; tr.w += sr[o][l][3];
        }
        const float inv = 1.0f / (float)(cnt > 1 ? cnt : 1);
        ushort4 ue, ur;
        ue.x = f2bf(te.x * inv); ue.y = f2bf(te.y * inv);
        ue.z = f2bf(te.z * inv); ue.w = f2bf(te.w * inv);
        ur.x = f2bf(tr.x * inv); ur.y = f2bf(tr.y * inv);
        ur.z = f2bf(tr.z * inv); ur.w = f2bf(tr.w * inv);
        *(ushort4*)(xrow + 128 + l * 4) = ue;
        *(ushort4*)(xrow + 256 + l * 4) = ur;
    } else if (threadIdx.x < 64) {
        const int l  = threadIdx.x - 32;
        const int c2 = l * 4;
        const int ent = entities[node];
        const float4 v = *(const float4*)(ent_emb + (size_t)ent * EMB + c2);
        ushort4 u;
        u.x = f2bf(v.x); u.y = f2bf(v.y); u.z = f2bf(v.z); u.w = f2bf(v.w);
        *(ushort4*)(xrow + c2) = u;
    }
}

// ---------------------------------------------------------------------------
// K2: fused MLP. Block = 32 H-rows (16 pairs), 4 waves, 256 threads.
// Phase 1: h = relu(Xcat @ Wb1^T + bias1) for 32 rows x 256 cols.
//   wave w: rows (w&1)*16, cols (w>>1)*128 (8 n-tiles, acc 8xf32x4).
//   Result -> LDS [32][LDP] bf16 (pad so phase-2 row-pair stride = 4 words mod 32).
// Phase 2: pair = relu(h_pairs @ Wb2^T + b_r), K=512 from LDS.
//   A2 row p = [h[2p] | h[2p+1]]: kb<8 -> row 2*lm col kb*32+lk; kb>=8 row 2*lm+1.
//   wave w: all 16 pairs x cols w*64 (4 n-tiles, acc 4xf32x4).
// MFMA frags: A/B lane (m|n=l&15, k-octet=l>>4); C/D col=l&15, row=(l>>4)*4+j.
// ---------------------------------------------------------------------------
__global__ __launch_bounds__(256) void k_mlp(
    const ushort* __restrict__ A,     // [NN][384] bf16 (Xcat)
    const ushort* __restrict__ B1,    // [256][384] bf16 (Wb1)
    const float* __restrict__ bias1,  // [256]
    const ushort* __restrict__ B2,    // [256][512] bf16 (Wb2)
    const float* __restrict__ br,     // [256]
    float* __restrict__ out)          // [NN/2][256] f32
{
    __shared__ ushort h_lds[32][LDP];

    const int wave = threadIdx.x >> 6;
    const int lane = threadIdx.x & 63;
    const int lm = lane & 15;
    const int lk = (lane >> 4) * 8;
    const int r0 = (lane >> 4) * 4;
    const int brow0 = blockIdx.x * 32;     // H-row base
    const int p0    = blockIdx.x * 16;     // pair base

    // ---------------- phase 1 ----------------
    {
        const int m0 = (wave & 1) * 16;            // local row base
        const int n0 = (wave >> 1) * 128;          // col base
        const ushort* Ap = A + (size_t)(brow0 + m0 + lm) * 384 + lk;

        f32x4 acc[8];
        #pragma unroll
        for (int ni = 0; ni < 8; ++ni) acc[ni] = (f32x4){0.f, 0.f, 0.f, 0.f};

        #pragma unroll 4
        for (int kb = 0; kb < 12; ++kb) {
            const bf16x8 a = *(const bf16x8*)(Ap + kb * 32);
            #pragma unroll
            for (int ni = 0; ni < 8; ++ni) {
                const bf16x8 b = *(const bf16x8*)(B1 + (size_t)(n0 + 16 * ni + lm) * 384 + kb * 32 + lk);
                acc[ni] = __builtin_amdgcn_mfma_f32_16x16x32_bf16(a, b, acc[ni], 0, 0, 0);
            }
        }

        #pragma unroll
        for (int ni = 0; ni < 8; ++ni) {
            const int col = n0 + 16 * ni + lm;
            const float bv = bias1[col];
            #pragma unroll
            for (int j = 0; j < 4; ++j) {
                const float v = fmaxf(acc[ni][j] + bv, 0.f);
                h_lds[m0 + r0 + j][col] = f2bf(v);
            }
        }
    }
    __syncthreads();

    // ---------------- phase 2 ----------------
    {
        const int n0 = wave * 64;

        f32x4 acc[4];
        #pragma unroll
        for (int ni = 0; ni < 4; ++ni) acc[ni] = (f32x4){0.f, 0.f, 0.f, 0.f};

        #pragma unroll 4
        for (int kb = 0; kb < 16; ++kb) {
            const int hi   = kb >> 3;                   // 0: h[2p], 1: h[2p+1]
            const int kcol = (kb & 7) * 32 + lk;
            const bf16x8 a = *(const bf16x8*)(&h_lds[2 * lm + hi][kcol]);
            #pragma unroll
            for (int ni = 0; ni < 4; ++ni) {
                const bf16x8 b = *(const bf16x8*)(B2 + (size_t)(n0 + 16 * ni + lm) * 512 + kb * 32 + lk);
                acc[ni] = __builtin_amdgcn_mfma_f32_16x16x32_bf16(a, b, acc[ni], 0, 0, 0);
            }
        }

        #pragma unroll
        for (int ni = 0; ni < 4; ++ni) {
            const int col = n0 + 16 * ni + lm;
            const float bv = br[col];
            #pragma unroll
            for (int j = 0; j < 4; ++j) {
                const int p = p0 + r0 + j;
                out[(size_t)p * 256 + col] = fmaxf(acc[ni][j] + bv, 0.f);
            }
        }
    }
}

// ---------------------------------------------------------------------------
extern "C" void kernel_launch(void* const* d_in, const int* in_sizes, int n_in,
                              void* d_out, int out_size, void* d_ws, size_t ws_size,
                              hipStream_t stream) {
    const int*   entities = (const int*)d_in[0];
    const int*   nbr_ent  = (const int*)d_in[1];
    const int*   nbr_rel  = (const int*)d_in[2];
    const int*   offsets  = (const int*)d_in[3];
    const float* ent_emb  = (const float*)d_in[4];
    const float* rel_emb  = (const float*)d_in[5];
    const float* W_t      = (const float*)d_in[6];
    const float* b_t      = (const float*)d_in[7];
    const float* W_n      = (const float*)d_in[8];
    const float* b_n      = (const float*)d_in[9];
    const float* W_r      = (const float*)d_in[10];
    const float* b_r      = (const float*)d_in[11];
    float* out = (float*)d_out;

    char* ws = (char*)d_ws;
    ushort* Xcat  = (ushort*)(ws);                  // 8192*384*2 = 6291456
    ushort* Wb1   = (ushort*)(ws + 6291456);        // 256*384*2  = 196608
    ushort* Wb2   = (ushort*)(ws + 6488064);        // 256*512*2  = 262144
    float*  bias1 = (float*)(ws + 6750208);         // 1024

    hipLaunchKernelGGL(k_agg_prep, dim3(NN + 256), dim3(256), 0, stream,
                       entities, nbr_ent, nbr_rel, offsets, ent_emb, rel_emb,
                       W_t, W_n, b_t, b_n, W_r, Xcat, Wb1, bias1, Wb2);
    hipLaunchKernelGGL(k_mlp, dim3(NN / 32), dim3(256), 0, stream,
                       Xcat, Wb1, bias1, Wb2, b_r, out);
}

// Round 8
// 76.597 us; speedup vs baseline: 1.0731x; 1.0731x over previous
//
#include <hip/hip_runtime.h>

#define NN 8192      // nodes (2 * batch)
#define NEDGE 524288 // total ragged neighbors
#define EMB 128
#define TILE 512     // edge-index LDS tile

typedef __attribute__((ext_vector_type(8))) short bf16x8;
typedef __attribute__((ext_vector_type(4))) float f32x4;

__device__ __forceinline__ ushort f2bf(float f) {
    union { float f; uint u; } v; v.f = f;
    return (ushort)((v.u + 0x7FFF + ((v.u >> 16) & 1)) >> 16);  // RNE
}

// ---------------------------------------------------------------------------
// K1: fused prep + ragged aggregation.
//  blocks [0,NN): one block per node, 256 threads = 8 groups x 32 lanes.
//    Stage 1: edge indices -> LDS (coalesced; kills the idx->gather dep chain).
//    Stage 2: each group walks LDS indices stride-8, 4-way unrolled branchless
//             (clamped idx + 0/1 FMA weight) -> 8 outstanding 16B gathers/lane.
//    Output row: Xcat[node] = bf16[ ent_row(128) | ne_mean(128) | nr_mean(128) ]
//  blocks [NN,NN+256): weight prep (bf16 convert, native [n][k] layout).
// ---------------------------------------------------------------------------
__global__ __launch_bounds__(256) void k_agg_prep(
    const int* __restrict__ entities,
    const int* __restrict__ nbr_ent,
    const int* __restrict__ nbr_rel,
    const int* __restrict__ offsets,
    const float* __restrict__ ent_emb,
    const float* __restrict__ rel_emb,
    const float* __restrict__ Wt,   // [256][128]
    const float* __restrict__ Wn,   // [256][256]
    const float* __restrict__ bt,
    const float* __restrict__ bn,
    const float* __restrict__ Wr,   // [256][512]
    ushort* __restrict__ Xcat,      // [NN][384] bf16
    ushort* __restrict__ Wb1,       // [256][384] bf16
    float* __restrict__ bias1,      // [256]
    ushort* __restrict__ Wb2)       // [256][512] bf16
{
    const int blk = blockIdx.x;
    if (blk >= NN) {                      // ---- weight-prep blocks ----
        const int j = blk - NN;           // 0..255
        const int t = threadIdx.x;
        for (int c = t; c < 384; c += 256) {
            const float v = (c < 128) ? Wt[(size_t)j * 128 + c]
                                      : Wn[(size_t)j * 256 + (c - 128)];
            Wb1[(size_t)j * 384 + c] = f2bf(v);
        }
        for (int c = t; c < 512; c += 256)
            Wb2[(size_t)j * 512 + c] = f2bf(Wr[(size_t)j * 512 + c]);
        if (t == 0) bias1[j] = bt[j] + bn[j];
        return;
    }

    // ---- aggregation blocks ----
    const int node  = blk;
    const int start = offsets[node];
    const int end   = (node + 1 < NN) ? offsets[node + 1] : NEDGE;
    const int cnt   = end - start;

    const int g    = threadIdx.x >> 5;   // 0..7
    const int lane = threadIdx.x & 31;   // 0..31
    const int c    = lane * 4;

    __shared__ int   sie[TILE];
    __shared__ int   sir[TILE];
    __shared__ float se[8][32][4];
    __shared__ float sr[8][32][4];

    float4 ae = make_float4(0.f, 0.f, 0.f, 0.f);
    float4 ar = make_float4(0.f, 0.f, 0.f, 0.f);

    for (int tb = start; tb < end; tb += TILE) {
        const int n = min(end - tb, TILE);
        __syncthreads();                                   // sie reusable
        for (int i = threadIdx.x; i < n; i += 256) {
            sie[i] = nbr_ent[tb + i];
            sir[i] = nbr_rel[tb + i];
        }
        __syncthreads();

        for (int i = g; i < n; i += 32) {
            // slots i, i+8, i+16, i+24 — branchless, loads always issued
            const int v1 = (i +  8 < n), v2 = (i + 16 < n), v3 = (i + 24 < n);
            const int i1 = v1 ? i +  8 : i;
            const int i2 = v2 ? i + 16 : i;
            const int i3 = v3 ? i + 24 : i;
            const float m1 = (float)v1, m2 = (float)v2, m3 = (float)v3;

            const float4 e0 = *(const float4*)(ent_emb + (size_t)sie[i ] * EMB + c);
            const float4 e1 = *(const float4*)(ent_emb + (size_t)sie[i1] * EMB + c);
            const float4 e2 = *(const float4*)(ent_emb + (size_t)sie[i2] * EMB + c);
            const float4 e3 = *(const float4*)(ent_emb + (size_t)sie[i3] * EMB + c);
            const float4 r0 = *(const float4*)(rel_emb + (size_t)sir[i ] * EMB + c);
            const float4 r1 = *(const float4*)(rel_emb + (size_t)sir[i1] * EMB + c);
            const float4 r2 = *(const float4*)(rel_emb + (size_t)sir[i2] * EMB + c);
            const float4 r3 = *(const float4*)(rel_emb + (size_t)sir[i3] * EMB + c);

            ae.x += e0.x; ae.y += e0.y; ae.z += e0.z; ae.w += e0.w;
            ar.x += r0.x; ar.y += r0.y; ar.z += r0.z; ar.w += r0.w;
            ae.x = fmaf(m1, e1.x, ae.x); ae.y = fmaf(m1, e1.y, ae.y);
            ae.z = fmaf(m1, e1.z, ae.z); ae.w = fmaf(m1, e1.w, ae.w);
            ar.x = fmaf(m1, r1.x, ar.x); ar.y = fmaf(m1, r1.y, ar.y);
            ar.z = fmaf(m1, r1.z, ar.z); ar.w = fmaf(m1, r1.w, ar.w);
            ae.x = fmaf(m2, e2.x, ae.x); ae.y = fmaf(m2, e2.y, ae.y);
            ae.z = fmaf(m2, e2.z, ae.z); ae.w = fmaf(m2, e2.w, ae.w);
            ar.x = fmaf(m2, r2.x, ar.x); ar.y = fmaf(m2, r2.y, ar.y);
            ar.z = fmaf(m2, r2.z, ar.z); ar.w = fmaf(m2, r2.w, ar.w);
            ae.x = fmaf(m3, e3.x, ae.x); ae.y = fmaf(m3, e3.y, ae.y);
            ae.z = fmaf(m3, e3.z, ae.z); ae.w = fmaf(m3, e3.w, ae.w);
            ar.x = fmaf(m3, r3.x, ar.x); ar.y = fmaf(m3, r3.y, ar.y);
            ar.z = fmaf(m3, r3.z, ar.z); ar.w = fmaf(m3, r3.w, ar.w);
        }
    }

    se[g][lane][0] = ae.x; se[g][lane][1] = ae.y;
    se[g][lane][2] = ae.z; se[g][lane][3] = ae.w;
    sr[g][lane][0] = ar.x; sr[g][lane][1] = ar.y;
    sr[g][lane][2] = ar.z; sr[g][lane][3] = ar.w;
    __syncthreads();

    ushort* xrow = Xcat + (size_t)node * 384;
    if (threadIdx.x < 32) {
        const int l = threadIdx.x;
        float4 te = make_float4(0.f, 0.f, 0.f, 0.f);
        float4 tr = make_float4(0.f, 0.f, 0.f, 0.f);
        #pragma unroll
        for (int o = 0; o < 8; ++o) {
            te.x += se[o][l][0]; te.y += se[o][l][1];
            te.z += se[o][l][2]; te.w += se[o][l][3];
            tr.x += sr[o][l][0]; tr.y += sr[o][l][1];
            tr.z += sr[o][l][2]; tr.w += sr[o][l][3];
        }
        const float inv = 1.0f / (float)(cnt > 1 ? cnt : 1);
        ushort4 ue, ur;
        ue.x = f2bf(te.x * inv); ue.y = f2bf(te.y * inv);
        ue.z = f2bf(te.z * inv); ue.w = f2bf(te.w * inv);
        ur.x = f2bf(tr.x * inv); ur.y = f2bf(tr.y * inv);
        ur.z = f2bf(tr.z * inv); ur.w = f2bf(tr.w * inv);
        *(ushort4*)(xrow + 128 + l * 4) = ue;
        *(ushort4*)(xrow + 256 + l * 4) = ur;
    } else if (threadIdx.x < 64) {
        const int l  = threadIdx.x - 32;
        const int c2 = l * 4;
        const int ent = entities[node];
        const float4 v = *(const float4*)(ent_emb + (size_t)ent * EMB + c2);
        ushort4 u;
        u.x = f2bf(v.x); u.y = f2bf(v.y); u.z = f2bf(v.z); u.w = f2bf(v.w);
        *(ushort4*)(xrow + c2) = u;
    }
}

// ---------------------------------------------------------------------------
// K2: h = relu(Xcat @ Wb1^T + bias1), bf16 MFMA 16x16x32, f32 accum.
// Wave tile 16(M) x 64(N); block = 4 waves in M -> 64x64 tile.
// A/B frags: lane (m|n = l&15, k-octet = l>>4) -> 16B contiguous [row][k].
// C/D: col=l&15, row=(l>>4)*4+reg  [guide-verified m89/m91].
// ---------------------------------------------------------------------------
__global__ __launch_bounds__(256) void k_gemm1(
    const ushort* __restrict__ A,     // [NN][384] bf16
    const ushort* __restrict__ B,     // [256][384] bf16
    const float* __restrict__ bias,   // [256]
    ushort* __restrict__ H)           // [NN][256] bf16
{
    const int wave = threadIdx.x >> 6;
    const int lane = threadIdx.x & 63;
    const int m0 = blockIdx.x * 64 + wave * 16;
    const int n0 = blockIdx.y * 64;
    const int lm = lane & 15;
    const int lk = (lane >> 4) * 8;

    const ushort* Ap  = A + (size_t)(m0 + lm) * 384 + lk;
    const ushort* Bp0 = B + (size_t)(n0 +  0 + lm) * 384 + lk;
    const ushort* Bp1 = B + (size_t)(n0 + 16 + lm) * 384 + lk;
    const ushort* Bp2 = B + (size_t)(n0 + 32 + lm) * 384 + lk;
    const ushort* Bp3 = B + (size_t)(n0 + 48 + lm) * 384 + lk;

    f32x4 acc0 = {0.f, 0.f, 0.f, 0.f};
    f32x4 acc1 = {0.f, 0.f, 0.f, 0.f};
    f32x4 acc2 = {0.f, 0.f, 0.f, 0.f};
    f32x4 acc3 = {0.f, 0.f, 0.f, 0.f};

    #pragma unroll
    for (int kb = 0; kb < 12; ++kb) {
        const bf16x8 a  = *(const bf16x8*)(Ap  + kb * 32);
        const bf16x8 b0 = *(const bf16x8*)(Bp0 + kb * 32);
        const bf16x8 b1 = *(const bf16x8*)(Bp1 + kb * 32);
        const bf16x8 b2 = *(const bf16x8*)(Bp2 + kb * 32);
        const bf16x8 b3 = *(const bf16x8*)(Bp3 + kb * 32);
        acc0 = __builtin_amdgcn_mfma_f32_16x16x32_bf16(a, b0, acc0, 0, 0, 0);
        acc1 = __builtin_amdgcn_mfma_f32_16x16x32_bf16(a, b1, acc1, 0, 0, 0);
        acc2 = __builtin_amdgcn_mfma_f32_16x16x32_bf16(a, b2, acc2, 0, 0, 0);
        acc3 = __builtin_amdgcn_mfma_f32_16x16x32_bf16(a, b3, acc3, 0, 0, 0);
    }

    const int r0 = (lane >> 4) * 4;
    f32x4 accs[4] = {acc0, acc1, acc2, acc3};
    #pragma unroll
    for (int ni = 0; ni < 4; ++ni) {
        const int col = n0 + ni * 16 + lm;
        const float bv = bias[col];
        #pragma unroll
        for (int j = 0; j < 4; ++j) {
            const int row = m0 + r0 + j;
            const float v = fmaxf(accs[ni][j] + bv, 0.f);
            H[(size_t)row * 256 + col] = f2bf(v);
        }
    }
}

// ---------------------------------------------------------------------------
// K3: pair = relu(H2 @ Wb2^T + b_r), H2 = H viewed [NN/2][512].
// ---------------------------------------------------------------------------
__global__ __launch_bounds__(256) void k_gemm2(
    const ushort* __restrict__ A,     // [NN/2][512] bf16
    const ushort* __restrict__ B,     // [256][512] bf16
    const float* __restrict__ bias,   // [256]
    float* __restrict__ out)          // [NN/2][256] f32
{
    const int wave = threadIdx.x >> 6;
    const int lane = threadIdx.x & 63;
    const int m0 = blockIdx.x * 64 + wave * 16;
    const int n0 = blockIdx.y * 64;
    const int lm = lane & 15;
    const int lk = (lane >> 4) * 8;

    const ushort* Ap  = A + (size_t)(m0 + lm) * 512 + lk;
    const ushort* Bp0 = B + (size_t)(n0 +  0 + lm) * 512 + lk;
    const ushort* Bp1 = B + (size_t)(n0 + 16 + lm) * 512 + lk;
    const ushort* Bp2 = B + (size_t)(n0 + 32 + lm) * 512 + lk;
    const ushort* Bp3 = B + (size_t)(n0 + 48 + lm) * 512 + lk;

    f32x4 acc0 = {0.f, 0.f, 0.f, 0.f};
    f32x4 acc1 = {0.f, 0.f, 0.f, 0.f};
    f32x4 acc2 = {0.f, 0.f, 0.f, 0.f};
    f32x4 acc3 = {0.f, 0.f, 0.f, 0.f};

    #pragma unroll
    for (int kb = 0; kb < 16; ++kb) {
        const bf16x8 a  = *(const bf16x8*)(Ap  + kb * 32);
        const bf16x8 b0 = *(const bf16x8*)(Bp0 + kb * 32);
        const bf16x8 b1 = *(const bf16x8*)(Bp1 + kb * 32);
        const bf16x8 b2 = *(const bf16x8*)(Bp2 + kb * 32);
        const bf16x8 b3 = *(const bf16x8*)(Bp3 + kb * 32);
        acc0 = __builtin_amdgcn_mfma_f32_16x16x32_bf16(a, b0, acc0, 0, 0, 0);
        acc1 = __builtin_amdgcn_mfma_f32_16x16x32_bf16(a, b1, acc1, 0, 0, 0);
        acc2 = __builtin_amdgcn_mfma_f32_16x16x32_bf16(a, b2, acc2, 0, 0, 0);
        acc3 = __builtin_amdgcn_mfma_f32_16x16x32_bf16(a, b3, acc3, 0, 0, 0);
    }

    const int r0 = (lane >> 4) * 4;
    f32x4 accs[4] = {acc0, acc1, acc2, acc3};
    #pragma unroll
    for (int ni = 0; ni < 4; ++ni) {
        const int col = n0 + ni * 16 + lm;
        const float bv = bias[col];
        #pragma unroll
        for (int j = 0; j < 4; ++j) {
            const int row = m0 + r0 + j;
            out[(size_t)row * 256 + col] = fmaxf(accs[ni][j] + bv, 0.f);
        }
    }
}

// ---------------------------------------------------------------------------
extern "C" void kernel_launch(void* const* d_in, const int* in_sizes, int n_in,
                              void* d_out, int out_size, void* d_ws, size_t ws_size,
                              hipStream_t stream) {
    const int*   entities = (const int*)d_in[0];
    const int*   nbr_ent  = (const int*)d_in[1];
    const int*   nbr_rel  = (const int*)d_in[2];
    const int*   offsets  = (const int*)d_in[3];
    const float* ent_emb  = (const float*)d_in[4];
    const float* rel_emb  = (const float*)d_in[5];
    const float* W_t      = (const float*)d_in[6];
    const float* b_t      = (const float*)d_in[7];
    const float* W_n      = (const float*)d_in[8];
    const float* b_n      = (const float*)d_in[9];
    const float* W_r      = (const float*)d_in[10];
    const float* b_r      = (const float*)d_in[11];
    float* out = (float*)d_out;

    char* ws = (char*)d_ws;
    ushort* Xcat  = (ushort*)(ws);                  // 8192*384*2 = 6291456
    ushort* H     = (ushort*)(ws + 6291456);        // 8192*256*2 = 4194304
    ushort* Wb1   = (ushort*)(ws + 10485760);       // 256*384*2  = 196608
    ushort* Wb2   = (ushort*)(ws + 10682368);       // 256*512*2  = 262144
    float*  bias1 = (float*)(ws + 10944512);        // 1024

    hipLaunchKernelGGL(k_agg_prep, dim3(NN + 256), dim3(256), 0, stream,
                       entities, nbr_ent, nbr_rel, offsets, ent_emb, rel_emb,
                       W_t, W_n, b_t, b_n, W_r, Xcat, Wb1, bias1, Wb2);
    hipLaunchKernelGGL(k_gemm1, dim3(NN / 64, 4), dim3(256), 0, stream,
                       Xcat, Wb1, bias1, H);
    hipLaunchKernelGGL(k_gemm2, dim3(NN / 2 / 64, 4), dim3(256), 0, stream,
                       H, Wb2, b_r, out);
}